// Round 12
// baseline (17.793 us; speedup 1.0000x reference)
//
#include <hip/hip_runtime.h>

#define NUM_NODES 10000
#define TSTEPS 1440
#define VCOLS 360          // 1440/4 float4 columns
#define PVC 364            // padded f4 row stride: 5824 B = 91 cache lines
#define NPART 500          // partial rows (one per stage-1 block)
#define RPB 20             // rows per block: 500 * 20 = 10000 exactly

typedef float f4v __attribute__((ext_vector_type(4)));

__device__ __forceinline__ void f4add(float4& a, const float4 b) {
    a.x += b.x; a.y += b.y; a.z += b.z; a.w += b.w;
}

// ROUND 12: S1 software-pipelined so per-wave in-flight loads never drain
// to zero (r11 split: S1 = 12.9us @ 4.46 TB/s, S2 = 2.7us). Old loop was
// issue-8 / waitcnt / consume -> the memory pipe drained every iteration and
// ~6 waves/CU couldn't cover the bubble. New: issue A(8)+B(8), consume A
// (compiler emits vmcnt(8)), issue C(4), consume B, consume C. Also 500
// blocks (2/CU for 244 CUs) so no CU idles. NT loads kept (r11: -1.4us).

// Stage 1: block b sums rows [20b, 20b+20) -> part[b][0..359].
__global__ __launch_bounds__(384) void partial_sum_kernel(
        const float* __restrict__ noise, float4* __restrict__ part) {
    int vc = threadIdx.x;            // 0..383 (360..383 idle)
    int b  = blockIdx.x;             // 0..499
    if (vc < VCOLS) {
        const f4v* p = (const f4v*)noise + (size_t)b * RPB * VCOLS + vc;
        // batch A: rows 0..7 ; batch B: rows 8..15 ; batch C: rows 16..19
        f4v a0 = __builtin_nontemporal_load(p + 0 * VCOLS);
        f4v a1 = __builtin_nontemporal_load(p + 1 * VCOLS);
        f4v a2 = __builtin_nontemporal_load(p + 2 * VCOLS);
        f4v a3 = __builtin_nontemporal_load(p + 3 * VCOLS);
        f4v a4 = __builtin_nontemporal_load(p + 4 * VCOLS);
        f4v a5 = __builtin_nontemporal_load(p + 5 * VCOLS);
        f4v a6 = __builtin_nontemporal_load(p + 6 * VCOLS);
        f4v a7 = __builtin_nontemporal_load(p + 7 * VCOLS);
        f4v b0 = __builtin_nontemporal_load(p + 8 * VCOLS);
        f4v b1 = __builtin_nontemporal_load(p + 9 * VCOLS);
        f4v b2 = __builtin_nontemporal_load(p + 10 * VCOLS);
        f4v b3 = __builtin_nontemporal_load(p + 11 * VCOLS);
        f4v b4 = __builtin_nontemporal_load(p + 12 * VCOLS);
        f4v b5 = __builtin_nontemporal_load(p + 13 * VCOLS);
        f4v b6 = __builtin_nontemporal_load(p + 14 * VCOLS);
        f4v b7 = __builtin_nontemporal_load(p + 15 * VCOLS);
        // consume A while B is outstanding (vmcnt(8))
        f4v sA = ((a0 + a1) + (a2 + a3)) + ((a4 + a5) + (a6 + a7));
        // issue tail batch C before consuming B
        f4v c0 = __builtin_nontemporal_load(p + 16 * VCOLS);
        f4v c1 = __builtin_nontemporal_load(p + 17 * VCOLS);
        f4v c2 = __builtin_nontemporal_load(p + 18 * VCOLS);
        f4v c3 = __builtin_nontemporal_load(p + 19 * VCOLS);
        f4v sB = ((b0 + b1) + (b2 + b3)) + ((b4 + b5) + (b6 + b7));
        f4v sC = (c0 + c1) + (c2 + c3);
        ((f4v*)part)[(size_t)b * PVC + vc] = sA + sB + sC;
    }
}

// Stage 2: byte-identical to round 9 (except NPART now 500 -> loop bounds).
// 90 blocks x 256 threads; thread (c4 = tid&3, jr = tid>>2) reads rows
// j = jr + 64k of its f4-column; LDS tree + wave-0 shuffle + fused finalize.
// overall[t] = 0.8*colmean + 0.5 + 0.3*sin(2pi*(10/3600)*time[t])
//   (mean over nodes of sin(theta_t + i*2pi/N) is exactly 0: equally spaced
//    phases over a full circle -> sum of N-th roots of unity = 0)
// encrypted[t] = sin(0.5*overall[t]); out = [encrypted(1440) | overall(1440)]
__global__ __launch_bounds__(256, 4) void reduce_finalize_kernel(
        const float* __restrict__ time_tensor,
        const float4* __restrict__ part,
        float* __restrict__ out) {
    int tid = threadIdx.x;
    int c4  = tid & 3;               // f4-col within tile (0..3)
    int jr  = tid >> 2;              // 0..63
    int c4g = blockIdx.x * 4 + c4;   // global f4-col 0..359

    const float4* q = part + c4g;
    float4 a0 = make_float4(0.f, 0.f, 0.f, 0.f), a1 = a0;
    #pragma unroll
    for (int k = 0; k < 3; ++k) {    // j = jr+128k, jr+128k+64  (max 447)
        float4 u0 = q[(size_t)(jr + 128 * k) * PVC];
        float4 u1 = q[(size_t)(jr + 128 * k + 64) * PVC];
        f4add(a0, u0); f4add(a1, u1);
    }
    {                                // tail: j = jr+384; j = jr+448 if jr<52
        float4 u0 = q[(size_t)(jr + 384) * PVC];
        f4add(a0, u0);
        if (jr < NPART - 448)
            f4add(a1, q[(size_t)(jr + 448) * PVC]);
    }
    f4add(a0, a1);

    __shared__ float4 red[64][4];
    red[jr][c4] = a0;
    __syncthreads();

    if (tid < 64) {                  // wave 0: jrs = tid>>2 (0..15), cc = tid&3
        int jrs = tid >> 2, cc = tid & 3;
        float4 s = red[jrs][cc];
        f4add(s, red[jrs + 16][cc]);
        f4add(s, red[jrs + 32][cc]);
        f4add(s, red[jrs + 48][cc]);
        #pragma unroll
        for (int off = 32; off >= 4; off >>= 1) {
            s.x += __shfl_down(s.x, off, 64);
            s.y += __shfl_down(s.y, off, 64);
            s.z += __shfl_down(s.z, off, 64);
            s.w += __shfl_down(s.w, off, 64);
        }
        if (tid < 4) {               // lane l holds f4-col blockIdx*4 + l
            int cg = blockIdx.x * 4 + tid;
            const float TWO_PI = 6.2831853071795864769f;
            const float BWF = 10.0f / 3600.0f;
            const float INV_N = 1.0f / NUM_NODES;
            float4 tm = ((const float4*)time_tensor)[cg];
            float4 ov, en;
            ov.x = 0.8f * (s.x * INV_N) + 0.5f + 0.3f * sinf(TWO_PI * BWF * tm.x);
            ov.y = 0.8f * (s.y * INV_N) + 0.5f + 0.3f * sinf(TWO_PI * BWF * tm.y);
            ov.z = 0.8f * (s.z * INV_N) + 0.5f + 0.3f * sinf(TWO_PI * BWF * tm.z);
            ov.w = 0.8f * (s.w * INV_N) + 0.5f + 0.3f * sinf(TWO_PI * BWF * tm.w);
            en.x = sinf(0.5f * ov.x);
            en.y = sinf(0.5f * ov.y);
            en.z = sinf(0.5f * ov.z);
            en.w = sinf(0.5f * ov.w);
            ((float4*)out)[TSTEPS / 4 + cg] = ov;   // overall   [1440, 2880)
            ((float4*)out)[cg] = en;                // encrypted [0, 1440)
        }
    }
}

extern "C" void kernel_launch(void* const* d_in, const int* in_sizes, int n_in,
                              void* d_out, int out_size, void* d_ws, size_t ws_size,
                              hipStream_t stream) {
    const float* time_tensor = (const float*)d_in[0];   // [1440]
    const float* noise       = (const float*)d_in[1];   // [10000, 1440]
    float* out   = (float*)d_out;                       // [2880]
    float4* part = (float4*)d_ws;                       // 500*364 f4 = 2.9 MB

    partial_sum_kernel<<<NPART, 384, 0, stream>>>(noise, part);
    reduce_finalize_kernel<<<VCOLS / 4, 256, 0, stream>>>(time_tensor, part, out);
}

// Round 13
// 16.339 us; speedup vs baseline: 1.0890x; 1.0890x over previous
//
#include <hip/hip_runtime.h>

#define NUM_NODES 10000
#define TSTEPS 1440
#define VCOLS 360          // 1440/4 float4 columns
#define PVC 364            // padded f4 row stride: 5824 B = 91 cache lines
#define NPART 250          // partial rows (one per stage-1 block)
#define RPB 40             // rows per block: 250 * 40 = 10000 exactly

typedef float f4v __attribute__((ext_vector_type(4)));

__device__ __forceinline__ void f4add(float4& a, const float4 b) {
    a.x += b.x; a.y += b.y; a.z += b.z; a.w += b.w;
}

// ROUND 13: single variable vs r11 (best, 16.09us) — S1's inner loop becomes
// a 3-buffer ROTATING PIPELINE so per-wave in-flight loads never drain below
// 16 until the tail (r11's loop drained to vmcnt(0) every 8 rows; the whole
// grid sawtooths in lockstep since all waves run identical code).
// Everything else byte-identical to r11: 250 blocks x 40 rows, NT loads,
// launch_bounds(384,4), same S2. Pre-committed read: win -> drain was the
// limiter; null -> ~4.5 TB/s is this pattern's read ceiling -> ROOFLINE.

// Stage 1: block b sums rows [40b, 40b+40) -> part[b][0..359].
__global__ __launch_bounds__(384, 4) void partial_sum_kernel(
        const float* __restrict__ noise, float4* __restrict__ part) {
    int vc = threadIdx.x;            // 0..383 (360..383 idle)
    int b  = blockIdx.x;             // 0..249
    if (vc >= VCOLS) return;
    const f4v* p = (const f4v*)noise + (size_t)b * RPB * VCOLS + vc;

    f4v A[8], B[8], C[8];            // 96 VGPR of load buffers (static idx)
    #pragma unroll
    for (int r = 0; r < 8; ++r) A[r] = __builtin_nontemporal_load(p + r * VCOLS);
    #pragma unroll
    for (int r = 0; r < 8; ++r) B[r] = __builtin_nontemporal_load(p + (8 + r) * VCOLS);
    #pragma unroll
    for (int r = 0; r < 8; ++r) C[r] = __builtin_nontemporal_load(p + (16 + r) * VCOLS);
    // 24 loads in flight; consume A at vmcnt(16)
    f4v s0 = ((A[0] + A[1]) + (A[2] + A[3])) + ((A[4] + A[5]) + (A[6] + A[7]));
    #pragma unroll
    for (int r = 0; r < 8; ++r) A[r] = __builtin_nontemporal_load(p + (24 + r) * VCOLS);
    // consume B at vmcnt(16)
    f4v s1 = ((B[0] + B[1]) + (B[2] + B[3])) + ((B[4] + B[5]) + (B[6] + B[7]));
    #pragma unroll
    for (int r = 0; r < 8; ++r) B[r] = __builtin_nontemporal_load(p + (32 + r) * VCOLS);
    // consume C at vmcnt(16), then the tail drains
    f4v s2 = ((C[0] + C[1]) + (C[2] + C[3])) + ((C[4] + C[5]) + (C[6] + C[7]));
    f4v s3 = ((A[0] + A[1]) + (A[2] + A[3])) + ((A[4] + A[5]) + (A[6] + A[7]));
    f4v s4 = ((B[0] + B[1]) + (B[2] + B[3])) + ((B[4] + B[5]) + (B[6] + B[7]));
    ((f4v*)part)[(size_t)b * PVC + vc] = (s0 + s1) + (s2 + s3) + s4;
}

// Stage 2: byte-identical to r11/r9. 90 blocks x 256 threads; thread
// (c4 = tid&3, jr = tid>>2) reads rows j = jr, jr+64, jr+128 (+ jr+192 if
// jr<58) of its f4-column; LDS tree + wave-0 shuffle + fused finalize.
// overall[t] = 0.8*colmean + 0.5 + 0.3*sin(2pi*(10/3600)*time[t])
//   (mean over nodes of sin(theta_t + i*2pi/N) is exactly 0: equally spaced
//    phases over a full circle -> sum of N-th roots of unity = 0)
// encrypted[t] = sin(0.5*overall[t]); out = [encrypted(1440) | overall(1440)]
__global__ __launch_bounds__(256, 4) void reduce_finalize_kernel(
        const float* __restrict__ time_tensor,
        const float4* __restrict__ part,
        float* __restrict__ out) {
    int tid = threadIdx.x;
    int c4  = tid & 3;               // f4-col within tile (0..3)
    int jr  = tid >> 2;              // 0..63
    int c4g = blockIdx.x * 4 + c4;   // global f4-col 0..359

    const float4* q = part + c4g;
    float4 a0 = q[(size_t)jr * PVC];
    float4 b0 = q[(size_t)(jr + 64) * PVC];
    float4 c0 = q[(size_t)(jr + 128) * PVC];
    f4add(a0, c0);
    if (jr < NPART - 192)            // j = jr+192 <= 249
        f4add(b0, q[(size_t)(jr + 192) * PVC]);
    f4add(a0, b0);

    __shared__ float4 red[64][4];
    red[jr][c4] = a0;
    __syncthreads();

    if (tid < 64) {                  // wave 0: jrs = tid>>2 (0..15), cc = tid&3
        int jrs = tid >> 2, cc = tid & 3;
        float4 s = red[jrs][cc];
        f4add(s, red[jrs + 16][cc]);
        f4add(s, red[jrs + 32][cc]);
        f4add(s, red[jrs + 48][cc]);
        #pragma unroll
        for (int off = 32; off >= 4; off >>= 1) {
            s.x += __shfl_down(s.x, off, 64);
            s.y += __shfl_down(s.y, off, 64);
            s.z += __shfl_down(s.z, off, 64);
            s.w += __shfl_down(s.w, off, 64);
        }
        if (tid < 4) {               // lane l holds f4-col blockIdx*4 + l
            int cg = blockIdx.x * 4 + tid;
            const float TWO_PI = 6.2831853071795864769f;
            const float BWF = 10.0f / 3600.0f;
            const float INV_N = 1.0f / NUM_NODES;
            float4 tm = ((const float4*)time_tensor)[cg];
            float4 ov, en;
            ov.x = 0.8f * (s.x * INV_N) + 0.5f + 0.3f * sinf(TWO_PI * BWF * tm.x);
            ov.y = 0.8f * (s.y * INV_N) + 0.5f + 0.3f * sinf(TWO_PI * BWF * tm.y);
            ov.z = 0.8f * (s.z * INV_N) + 0.5f + 0.3f * sinf(TWO_PI * BWF * tm.z);
            ov.w = 0.8f * (s.w * INV_N) + 0.5f + 0.3f * sinf(TWO_PI * BWF * tm.w);
            en.x = sinf(0.5f * ov.x);
            en.y = sinf(0.5f * ov.y);
            en.z = sinf(0.5f * ov.z);
            en.w = sinf(0.5f * ov.w);
            ((float4*)out)[TSTEPS / 4 + cg] = ov;   // overall   [1440, 2880)
            ((float4*)out)[cg] = en;                // encrypted [0, 1440)
        }
    }
}

extern "C" void kernel_launch(void* const* d_in, const int* in_sizes, int n_in,
                              void* d_out, int out_size, void* d_ws, size_t ws_size,
                              hipStream_t stream) {
    const float* time_tensor = (const float*)d_in[0];   // [1440]
    const float* noise       = (const float*)d_in[1];   // [10000, 1440]
    float* out   = (float*)d_out;                       // [2880]
    float4* part = (float4*)d_ws;                       // 250*364 f4 = 1.46 MB

    partial_sum_kernel<<<NPART, 384, 0, stream>>>(noise, part);
    reduce_finalize_kernel<<<VCOLS / 4, 256, 0, stream>>>(time_tensor, part, out);
}

// Round 14
// 16.102 us; speedup vs baseline: 1.1050x; 1.0147x over previous
//
#include <hip/hip_runtime.h>

#define NUM_NODES 10000
#define TSTEPS 1440
#define VCOLS 360          // 1440/4 float4 columns
#define PVC 364            // padded f4 row stride: 5824 B = 91 cache lines
#define NPART 250          // partial rows (one per stage-1 block)
#define RPB 40             // rows per block: 250 * 40 = 10000 exactly

typedef float f4v __attribute__((ext_vector_type(4)));

__device__ __forceinline__ void f4add(float4& a, const float4 b) {
    a.x += b.x; a.y += b.y; a.z += b.z; a.w += b.w;
}

// ROUND 14 (final tuning round): S1 reverted BYTE-IDENTICAL to r11 (best,
// 16.09us; S1 ~= 12.9us = empirical 4.5 TB/s pattern ceiling — ILP, TLP,
// NT, and drain hypotheses all individually falsified across r3-r13).
// Single variable: S2 gets 512 threads/block (2 rows/thread instead of 4)
// to double in-flight waves on its latency-bound strided reads.

// Stage 1: block b sums rows [40b, 40b+40) -> part[b][0..359].  (= r11)
__global__ __launch_bounds__(384, 4) void partial_sum_kernel(
        const float* __restrict__ noise, float4* __restrict__ part) {
    int vc = threadIdx.x;            // 0..383
    int b  = blockIdx.x;             // 0..249
    if (vc < VCOLS) {
        const f4v* p = (const f4v*)noise + (size_t)b * RPB * VCOLS + vc;
        f4v acc = (f4v)(0.0f);
        #pragma unroll 1             // keep 8 loads in flight, ~40 VGPR
        for (int it = 0; it < RPB / 8; ++it) {
            f4v v0 = __builtin_nontemporal_load(p + 0 * VCOLS);
            f4v v1 = __builtin_nontemporal_load(p + 1 * VCOLS);
            f4v v2 = __builtin_nontemporal_load(p + 2 * VCOLS);
            f4v v3 = __builtin_nontemporal_load(p + 3 * VCOLS);
            f4v v4 = __builtin_nontemporal_load(p + 4 * VCOLS);
            f4v v5 = __builtin_nontemporal_load(p + 5 * VCOLS);
            f4v v6 = __builtin_nontemporal_load(p + 6 * VCOLS);
            f4v v7 = __builtin_nontemporal_load(p + 7 * VCOLS);
            p += 8 * VCOLS;
            v0 += v1; v2 += v3; v4 += v5; v6 += v7;
            v0 += v2; v4 += v6;
            v0 += v4;
            acc += v0;
        }
        ((f4v*)part)[(size_t)b * PVC + vc] = acc;
    }
}

// Stage 2: 90 blocks x 512 threads (was 256). thread (c4 = tid&3,
// jr = tid>>2 in 0..127) reads rows jr and jr+128 (if < 250) of its
// f4-column — 4 consecutive lanes cover one 64B line (line-exact), 2
// independent loads/thread, 8 waves/block in flight (2x r11's TLP on a
// latency-bound stage). LDS tree 128->16, wave-0 shuffle, fused finalize.
// overall[t] = 0.8*colmean + 0.5 + 0.3*sin(2pi*(10/3600)*time[t])
//   (mean over nodes of sin(theta_t + i*2pi/N) is exactly 0: equally spaced
//    phases over a full circle -> sum of N-th roots of unity = 0)
// encrypted[t] = sin(0.5*overall[t]); out = [encrypted(1440) | overall(1440)]
__global__ __launch_bounds__(512, 2) void reduce_finalize_kernel(
        const float* __restrict__ time_tensor,
        const float4* __restrict__ part,
        float* __restrict__ out) {
    int tid = threadIdx.x;
    int c4  = tid & 3;               // f4-col within tile (0..3)
    int jr  = tid >> 2;              // 0..127
    int c4g = blockIdx.x * 4 + c4;   // global f4-col 0..359

    const float4* q = part + c4g;
    float4 a0 = make_float4(0.f, 0.f, 0.f, 0.f);
    if (jr < NPART)                  // rows 0..127 always; 128..249 partial
        a0 = q[(size_t)jr * PVC];
    if (jr < NPART - 128)            // j = jr+128 <= 249
        f4add(a0, q[(size_t)(jr + 128) * PVC]);

    __shared__ float4 red[128][4];
    red[jr][c4] = a0;
    __syncthreads();

    if (tid < 64) {                  // wave 0: jrs = tid>>2 (0..15), cc = tid&3
        int jrs = tid >> 2, cc = tid & 3;
        float4 s = red[jrs][cc];
        #pragma unroll
        for (int k = 1; k < 8; ++k) f4add(s, red[jrs + 16 * k][cc]);
        #pragma unroll
        for (int off = 32; off >= 4; off >>= 1) {
            s.x += __shfl_down(s.x, off, 64);
            s.y += __shfl_down(s.y, off, 64);
            s.z += __shfl_down(s.z, off, 64);
            s.w += __shfl_down(s.w, off, 64);
        }
        if (tid < 4) {               // lane l holds f4-col blockIdx*4 + l
            int cg = blockIdx.x * 4 + tid;
            const float TWO_PI = 6.2831853071795864769f;
            const float BWF = 10.0f / 3600.0f;
            const float INV_N = 1.0f / NUM_NODES;
            float4 tm = ((const float4*)time_tensor)[cg];
            float4 ov, en;
            ov.x = 0.8f * (s.x * INV_N) + 0.5f + 0.3f * sinf(TWO_PI * BWF * tm.x);
            ov.y = 0.8f * (s.y * INV_N) + 0.5f + 0.3f * sinf(TWO_PI * BWF * tm.y);
            ov.z = 0.8f * (s.z * INV_N) + 0.5f + 0.3f * sinf(TWO_PI * BWF * tm.z);
            ov.w = 0.8f * (s.w * INV_N) + 0.5f + 0.3f * sinf(TWO_PI * BWF * tm.w);
            en.x = sinf(0.5f * ov.x);
            en.y = sinf(0.5f * ov.y);
            en.z = sinf(0.5f * ov.z);
            en.w = sinf(0.5f * ov.w);
            ((float4*)out)[TSTEPS / 4 + cg] = ov;   // overall   [1440, 2880)
            ((float4*)out)[cg] = en;                // encrypted [0, 1440)
        }
    }
}

extern "C" void kernel_launch(void* const* d_in, const int* in_sizes, int n_in,
                              void* d_out, int out_size, void* d_ws, size_t ws_size,
                              hipStream_t stream) {
    const float* time_tensor = (const float*)d_in[0];   // [1440]
    const float* noise       = (const float*)d_in[1];   // [10000, 1440]
    float* out   = (float*)d_out;                       // [2880]
    float4* part = (float4*)d_ws;                       // 250*364 f4 = 1.46 MB

    partial_sum_kernel<<<NPART, 384, 0, stream>>>(noise, part);
    reduce_finalize_kernel<<<VCOLS / 4, 512, 0, stream>>>(time_tensor, part, out);
}